// Round 7
// baseline (500.479 us; speedup 1.0000x reference)
//
#include <hip/hip_runtime.h>

// BilateralFilter: 8 x 1024 x 1024 x 3 fp32, D=9 (radius 4), sigma_color =
// sigma_space = 75, reflect padding, taps with dy*dy+dx*dx <= 16 (49 live).
//
// Round 7: model says LDS-pipe-bound (R5: 49 ds_read_b128/wave-task = 125us
// of LDS pipe vs 52us VALU; measured 151us). Cut LDS instrs 49->29 per
// output via PV=2 vertical register blocking, with ZERO arrays (R4's scratch
// explosion came from runtime-indexed arrays) — named cA/cB/aA/aB only.
// Also reverts R6's poly exp2 (regression: v_exp_f32 is ~6 cyc, cheap).

namespace {
constexpr int Himg = 1024;
constexpr int Wimg = 1024;
constexpr int CHN  = 3;
constexpr int RAD  = 4;

constexpr int BXT = 64;              // tile width (one wave-row)
constexpr int PV  = 2;               // vertical outputs per thread
constexpr int BYT = 4 * PV;          // 4 waves x 2 rows = 8 output rows
constexpr int TW  = BXT + 2 * RAD;   // 72 px
constexpr int TH  = BYT + 2 * RAD;   // 16 rows
constexpr int NPX = TW * TH;         // 1152 staged pixels

constexpr float LOG2E = 1.4426950408889634f;
constexpr float COEFF = -0.5f / (75.0f * 75.0f);   // sigma_color == sigma_space
constexpr float KC2   = COEFF * LOG2E;             // exp2-domain coefficient (<0)

typedef float f4 __attribute__((ext_vector_type(4)));

// max |dx| such that dy^2+dx^2 <= 16; -1 if row unused. |dx|<=lim(dy) is
// EXACTLY the tap mask (no separate r2 check needed).
constexpr int lim(int dy) {
    int a = dy < 0 ? -dy : dy;
    return a == 0 ? 4 : a == 1 ? 3 : a == 2 ? 3 : a == 3 ? 2 : a == 4 ? 0 : -1;
}
constexpr int cmax(int a, int b) { return a > b ? a : b; }
}

__device__ __forceinline__ int reflect_idx(int i, int n) {
    i = (i < 0) ? -i : i;
    return (i >= n) ? (2 * n - 2 - i) : i;
}

// one tap: diff vs center c (pre-scaled), w = exp2(-diff^2 + KC2*r2),
// acc += nb*w (W lane of nb is 1.0 -> denominator rides along)
__device__ __forceinline__ void tap(f4& acc, const f4& c, const f4& nb,
                                    float kr2) {
    const float diff = fabsf(nb.x - c.x) + fabsf(nb.y - c.y) + fabsf(nb.z - c.z);
    const float w = __builtin_amdgcn_exp2f(fmaf(diff, -diff, kr2));
    acc += nb * w;
}

__global__ __launch_bounds__(256, 4)
void bilateral_kernel(const float* __restrict__ in, float* __restrict__ out) {
    __shared__ f4 tile[TH][TW];        // 16 x 72 x 16B = 18432 B

    const float SC     = sqrtf(-KC2);  // constant-folded; staged px = SC*v
    const float INV_SC = 1.0f / SC;

    const int tid = threadIdx.x;
    const int x0  = blockIdx.x * BXT;
    const int y0  = blockIdx.y * BYT;

    const float* __restrict__ img = in + (size_t)blockIdx.z * Himg * Wimg * CHN;

    // ---- stage RGBW tile (reflect halo): (r*SC, g*SC, b*SC, 1.0) ----
    for (int i = tid; i < NPX; i += 256) {
        const int row = i / TW;
        const int px  = i - row * TW;
        const int gy  = reflect_idx(y0 - RAD + row, Himg);
        const int gx  = reflect_idx(x0 - RAD + px,  Wimg);
        const float* p = img + ((size_t)gy * Wimg + gx) * CHN;
        f4 v;
        v.x = p[0] * SC;
        v.y = p[1] * SC;
        v.z = p[2] * SC;
        v.w = 1.0f;
        tile[row][px] = v;             // ds_write_b128
    }
    __syncthreads();

    // ---- each thread: 2 vertically-adjacent output pixels at column tx ----
    const int tx  = tid & 63;          // wave = one 64-px row pair
    const int wv  = tid >> 6;
    const int ly0 = wv * PV;           // tile row of output A (before +RAD)

    const f4 cA = tile[ly0 + RAD + 0][tx + RAD];
    const f4 cB = tile[ly0 + RAD + 1][tx + RAD];

    f4 aA = (f4){0.f, 0.f, 0.f, 0.f};
    f4 aB = (f4){0.f, 0.f, 0.f, 0.f};

#pragma unroll
    for (int sr = 0; sr < PV + 2 * RAD; ++sr) {        // 10 source rows
        const int dyA = sr - RAD;                      // tap offset for A
        const int dyB = sr - RAD - 1;                  // tap offset for B
        const int LA  = lim(dyA);                      // all compile-time
        const int LB  = lim(dyB);
        const int L   = cmax(LA, LB);
#pragma unroll
        for (int dx = -RAD; dx <= RAD; ++dx) {
            if (dx < -L || dx > L) continue;           // pruned: 58 reads total
            const f4 nb = tile[ly0 + sr][tx + RAD + dx];   // ds_read_b128
            if (dx >= -LA && dx <= LA)
                tap(aA, cA, nb, KC2 * (float)(dyA * dyA + dx * dx));
            if (dx >= -LB && dx <= LB)
                tap(aB, cB, nb, KC2 * (float)(dyB * dyB + dx * dx));
        }
    }

    const size_t oA =
        ((size_t)(blockIdx.z * Himg + y0 + ly0) * Wimg + (x0 + tx)) * CHN;
    const float invA = (1.0f / aA.w) * INV_SC;
    out[oA + 0] = aA.x * invA;
    out[oA + 1] = aA.y * invA;
    out[oA + 2] = aA.z * invA;

    const size_t oB = oA + (size_t)Wimg * CHN;
    const float invB = (1.0f / aB.w) * INV_SC;
    out[oB + 0] = aB.x * invB;
    out[oB + 1] = aB.y * invB;
    out[oB + 2] = aB.z * invB;
}

extern "C" void kernel_launch(void* const* d_in, const int* in_sizes, int n_in,
                              void* d_out, int out_size, void* d_ws, size_t ws_size,
                              hipStream_t stream) {
    const float* in = (const float*)d_in[0];
    float* out = (float*)d_out;

    const int B = in_sizes[0] / (Himg * Wimg * CHN);   // = 8

    dim3 grid(Wimg / BXT, Himg / BYT, B);              // 16 x 128 x 8
    dim3 block(256);
    bilateral_kernel<<<grid, block, 0, stream>>>(in, out);
}

// Round 8
// 297.754 us; speedup vs baseline: 1.6808x; 1.6808x over previous
//
#include <hip/hip_runtime.h>

// BilateralFilter: 8 x 1024 x 1024 x 3 fp32, D=9 (radius 4), sigma_color =
// sigma_space = 75, reflect padding, taps with dy*dy+dx*dx <= 16 (49 live).
//
// Round 8: single-variable A/B vs round 7. R7 (PV=2) spilled ~50 dw/thread
// (WRITE 950MB vs 98MB output) because __launch_bounds__(256,4) clamped the
// allocator to 64 VGPR while the scheduler's hoisted ds_read clusters need
// ~100+. Only change: launch_bounds min-waves 4 -> 2 (VGPR cap 256).
// LDS-byte model: PV=2 reads 464 B/px -> ~74us LDS floor; VALU ~55us.

namespace {
constexpr int Himg = 1024;
constexpr int Wimg = 1024;
constexpr int CHN  = 3;
constexpr int RAD  = 4;

constexpr int BXT = 64;              // tile width (one wave-row)
constexpr int PV  = 2;               // vertical outputs per thread
constexpr int BYT = 4 * PV;          // 4 waves x 2 rows = 8 output rows
constexpr int TW  = BXT + 2 * RAD;   // 72 px
constexpr int TH  = BYT + 2 * RAD;   // 16 rows
constexpr int NPX = TW * TH;         // 1152 staged pixels

constexpr float LOG2E = 1.4426950408889634f;
constexpr float COEFF = -0.5f / (75.0f * 75.0f);   // sigma_color == sigma_space
constexpr float KC2   = COEFF * LOG2E;             // exp2-domain coefficient (<0)

typedef float f4 __attribute__((ext_vector_type(4)));

// max |dx| such that dy^2+dx^2 <= 16; -1 if row unused. |dx|<=lim(dy) is
// EXACTLY the tap mask (no separate r2 check needed).
constexpr int lim(int dy) {
    int a = dy < 0 ? -dy : dy;
    return a == 0 ? 4 : a == 1 ? 3 : a == 2 ? 3 : a == 3 ? 2 : a == 4 ? 0 : -1;
}
constexpr int cmax(int a, int b) { return a > b ? a : b; }
}

__device__ __forceinline__ int reflect_idx(int i, int n) {
    i = (i < 0) ? -i : i;
    return (i >= n) ? (2 * n - 2 - i) : i;
}

// one tap: diff vs center c (pre-scaled), w = exp2(-diff^2 + KC2*r2),
// acc += nb*w (W lane of nb is 1.0 -> denominator rides along)
__device__ __forceinline__ void tap(f4& acc, const f4& c, const f4& nb,
                                    float kr2) {
    const float diff = fabsf(nb.x - c.x) + fabsf(nb.y - c.y) + fabsf(nb.z - c.z);
    const float w = __builtin_amdgcn_exp2f(fmaf(diff, -diff, kr2));
    acc += nb * w;
}

__global__ __launch_bounds__(256, 2)
void bilateral_kernel(const float* __restrict__ in, float* __restrict__ out) {
    __shared__ f4 tile[TH][TW];        // 16 x 72 x 16B = 18432 B

    const float SC     = sqrtf(-KC2);  // constant-folded; staged px = SC*v
    const float INV_SC = 1.0f / SC;

    const int tid = threadIdx.x;
    const int x0  = blockIdx.x * BXT;
    const int y0  = blockIdx.y * BYT;

    const float* __restrict__ img = in + (size_t)blockIdx.z * Himg * Wimg * CHN;

    // ---- stage RGBW tile (reflect halo): (r*SC, g*SC, b*SC, 1.0) ----
    for (int i = tid; i < NPX; i += 256) {
        const int row = i / TW;
        const int px  = i - row * TW;
        const int gy  = reflect_idx(y0 - RAD + row, Himg);
        const int gx  = reflect_idx(x0 - RAD + px,  Wimg);
        const float* p = img + ((size_t)gy * Wimg + gx) * CHN;
        f4 v;
        v.x = p[0] * SC;
        v.y = p[1] * SC;
        v.z = p[2] * SC;
        v.w = 1.0f;
        tile[row][px] = v;             // ds_write_b128
    }
    __syncthreads();

    // ---- each thread: 2 vertically-adjacent output pixels at column tx ----
    const int tx  = tid & 63;          // wave = one 64-px row pair
    const int wv  = tid >> 6;
    const int ly0 = wv * PV;           // tile row of output A (before +RAD)

    const f4 cA = tile[ly0 + RAD + 0][tx + RAD];
    const f4 cB = tile[ly0 + RAD + 1][tx + RAD];

    f4 aA = (f4){0.f, 0.f, 0.f, 0.f};
    f4 aB = (f4){0.f, 0.f, 0.f, 0.f};

#pragma unroll
    for (int sr = 0; sr < PV + 2 * RAD; ++sr) {        // 10 source rows
        const int dyA = sr - RAD;                      // tap offset for A
        const int dyB = sr - RAD - 1;                  // tap offset for B
        const int LA  = lim(dyA);                      // all compile-time
        const int LB  = lim(dyB);
        const int L   = cmax(LA, LB);
#pragma unroll
        for (int dx = -RAD; dx <= RAD; ++dx) {
            if (dx < -L || dx > L) continue;           // pruned: 58 reads total
            const f4 nb = tile[ly0 + sr][tx + RAD + dx];   // ds_read_b128
            if (dx >= -LA && dx <= LA)
                tap(aA, cA, nb, KC2 * (float)(dyA * dyA + dx * dx));
            if (dx >= -LB && dx <= LB)
                tap(aB, cB, nb, KC2 * (float)(dyB * dyB + dx * dx));
        }
    }

    const size_t oA =
        ((size_t)(blockIdx.z * Himg + y0 + ly0) * Wimg + (x0 + tx)) * CHN;
    const float invA = (1.0f / aA.w) * INV_SC;
    out[oA + 0] = aA.x * invA;
    out[oA + 1] = aA.y * invA;
    out[oA + 2] = aA.z * invA;

    const size_t oB = oA + (size_t)Wimg * CHN;
    const float invB = (1.0f / aB.w) * INV_SC;
    out[oB + 0] = aB.x * invB;
    out[oB + 1] = aB.y * invB;
    out[oB + 2] = aB.z * invB;
}

extern "C" void kernel_launch(void* const* d_in, const int* in_sizes, int n_in,
                              void* d_out, int out_size, void* d_ws, size_t ws_size,
                              hipStream_t stream) {
    const float* in = (const float*)d_in[0];
    float* out = (float*)d_out;

    const int B = in_sizes[0] / (Himg * Wimg * CHN);   // = 8

    dim3 grid(Wimg / BXT, Himg / BYT, B);              // 16 x 128 x 8
    dim3 block(256);
    bilateral_kernel<<<grid, block, 0, stream>>>(in, out);
}